// Round 2
// 209.812 us; speedup vs baseline: 1.0284x; 1.0284x over previous
//
#include <hip/hip_runtime.h>

// KAN-CNN: out[b,f,h,w] = sum_{dy,dx,c} R_{f,dy,dx,c}( xpad[b,c,h+dy-1,w+dx-1] )
// R(x) = P5(x)/(1+|x*Q(x)|).
//
// R6 = R5 with the compile failure fixed. gfx950 has no op_sel on VOP1 f16
// (CDNA dropped SDWA), so hi-half rcp via `v_rcp_f16_e64 op_sel:[1,1]` does
// not assemble. Use __builtin_amdgcn_rcph on each half instead; compiler
// emits lshr + v_rcp_f16 + v_pack_b32_f16 (~2 extra VALU / 2 taps).
// Everything else as R5:
//  - channel pairs (c,c+1) packed in one f16x2 lane value
//  - both Horner chains in v_pk_fma_f16 (full-rate 2x vs fp32)
//  - 1+|t| = v_and(0x7fff7fff) + v_pk_add_f16
//  - accumulate with v_dot2_f32_f16 (2 f16 MACs, fp32 accumulator) so the
//    288-term reduction keeps fp32 precision.
// Loads halve (f16 pairs), coeff scalar-load dwords halve. Vertical quad of
// pixels per thread; grid = 2048 blocks = 8 blocks/CU full residency.

typedef _Float16 h2 __attribute__((ext_vector_type(2)));

#define Bb 8
#define Cc 32
#define CP 16          // channel pairs
#define Hh 64
#define Ww 64
#define Ff 64

#define PW 66
#define PPLANE (PW * PW)
#define RPB 16         // rows per block = 4 quads * 4

#define XPADH_N (Bb * CP * PPLANE)   // 557,568 u32 (2.23 MB)
#define NCH_N   (Ff * 9 * CP * 6)    //  55,296 u32
#define DCH_N   (Ff * 9 * CP * 4)    //  36,864 u32

__global__ __launch_bounds__(256) void pad_h_kernel(
    const float* __restrict__ x,        // [B,C,64,64] f32
    unsigned* __restrict__ xpadh)       // [B,CP,66,66] f16x2 {c even, c odd}
{
    int idx = (int)blockIdx.x * 256 + (int)threadIdx.x;
    if (idx >= XPADH_N) return;
    int cell  = idx % PPLANE;
    int plane = idx / PPLANE;           // b*CP + c2
    int c2 = plane % CP;
    int b  = plane / CP;
    int hp = cell / PW, wp = cell % PW;
    float x0 = 0.0f, x1 = 0.0f;
    if (hp >= 1 && hp <= Hh && wp >= 1 && wp <= Ww) {
        const float* s = x + (((size_t)b * Cc + 2 * c2) * Hh + (hp - 1)) * Ww + (wp - 1);
        x0 = s[0];
        x1 = s[Hh * Ww];
    }
    h2 p; p.x = (_Float16)x0; p.y = (_Float16)x1;
    xpadh[idx] = __builtin_bit_cast(unsigned, p);
}

__global__ __launch_bounds__(256) void coef_h_kernel(
    const float* __restrict__ ncf,      // [F,3,3,C,6] f32
    const float* __restrict__ dcf,      // [F,3,3,C,4] f32
    unsigned* __restrict__ nch,         // [F,9,CP,6] f16x2
    unsigned* __restrict__ dch)         // [F,9,CP,4] f16x2
{
    int idx = (int)blockIdx.x * 256 + (int)threadIdx.x;
    if (idx < NCH_N) {
        int i  = idx % 6;
        int r  = idx / 6;
        int cp = r % CP;
        int fk = r / CP;                // f*9 + k2
        const float* s = ncf + ((size_t)fk * Cc + 2 * cp) * 6 + i;
        h2 p; p.x = (_Float16)s[0]; p.y = (_Float16)s[6];
        nch[idx] = __builtin_bit_cast(unsigned, p);
    } else if (idx < NCH_N + DCH_N) {
        int j  = idx - NCH_N;
        int i  = j % 4;
        int r  = j / 4;
        int cp = r % CP;
        int fk = r / CP;
        const float* s = dcf + ((size_t)fk * Cc + 2 * cp) * 4 + i;
        h2 p; p.x = (_Float16)s[0]; p.y = (_Float16)s[4];
        dch[j] = __builtin_bit_cast(unsigned, p);
    }
}

static __device__ __forceinline__ float dot2_acc(h2 a, h2 b, float c) {
#if __has_builtin(__builtin_amdgcn_fdot2)
    return __builtin_amdgcn_fdot2(a, b, c, false);
#else
    float r = c;
    asm("v_dot2_f32_f16 %0, %1, %2, %0" : "+v"(r) : "v"(a), "v"(b));
    return r;
#endif
}

__global__ __launch_bounds__(256) void kan_h_kernel(
    const unsigned* __restrict__ xpadh, // [B,CP,66,66] f16 channel pairs
    const unsigned* __restrict__ nch,   // [F,9,CP,6]
    const unsigned* __restrict__ dch,   // [F,9,CP,4]
    float* __restrict__ out)            // [B,F,H,W] f32
{
    const int t  = threadIdx.x;
    const int w  = t & 63;
    const int qr = t >> 6;                        // quad index 0..3
    const int h0 = (int)blockIdx.y * RPB + qr * 4;
    const int f  = (int)blockIdx.x;
    const int b  = (int)blockIdx.z;

    const unsigned* __restrict__ xp =
        xpadh + (size_t)b * CP * PPLANE + (h0 + 1) * PW + (w + 1);
    const unsigned* __restrict__ nc = nch + (size_t)f * 9 * CP * 6;
    const unsigned* __restrict__ dc = dch + (size_t)f * 9 * CP * 4;

    const h2 one = {(_Float16)1.0f, (_Float16)1.0f};

    float acc[4] = {0.0f, 0.0f, 0.0f, 0.0f};

#pragma unroll 1
    for (int cp = 0; cp < CP; ++cp, xp += PPLANE) {
        // 6 rows x 3 cols of channel-pair values cover the vertical quad.
        h2 r[6][3];
#pragma unroll
        for (int j = 0; j < 6; ++j)
#pragma unroll
            for (int dx = 0; dx < 3; ++dx)
                r[j][dx] = __builtin_bit_cast(h2, xp[(j - 1) * PW + (dx - 1)]);

#pragma unroll
        for (int dy = 0; dy < 3; ++dy) {
#pragma unroll
            for (int dx = 0; dx < 3; ++dx) {
                const int k2 = dy * 3 + dx;
                const unsigned* __restrict__ A  = nc + (k2 * CP + cp) * 6;
                const unsigned* __restrict__ Bq = dc + (k2 * CP + cp) * 4;
                // thread-uniform -> scalar loads; each f16x2 dword is a
                // VOP3P broadcast operand
                const h2 a0 = __builtin_bit_cast(h2, A[0]);
                const h2 a1 = __builtin_bit_cast(h2, A[1]);
                const h2 a2 = __builtin_bit_cast(h2, A[2]);
                const h2 a3 = __builtin_bit_cast(h2, A[3]);
                const h2 a4 = __builtin_bit_cast(h2, A[4]);
                const h2 a5 = __builtin_bit_cast(h2, A[5]);
                const h2 b0 = __builtin_bit_cast(h2, Bq[0]);
                const h2 b1 = __builtin_bit_cast(h2, Bq[1]);
                const h2 b2 = __builtin_bit_cast(h2, Bq[2]);
                const h2 b3 = __builtin_bit_cast(h2, Bq[3]);

#pragma unroll
                for (int p = 0; p < 4; ++p) {
                    h2 xv = r[dy + p][dx];

                    h2 n = __builtin_elementwise_fma(xv, a5, a4);
                    n = __builtin_elementwise_fma(n, xv, a3);
                    n = __builtin_elementwise_fma(n, xv, a2);
                    n = __builtin_elementwise_fma(n, xv, a1);
                    n = __builtin_elementwise_fma(n, xv, a0);

                    h2 q = __builtin_elementwise_fma(xv, b3, b2);
                    q = __builtin_elementwise_fma(q, xv, b1);
                    q = __builtin_elementwise_fma(q, xv, b0);

                    h2 tt = q * xv;                               // v_pk_mul_f16
                    unsigned au = __builtin_bit_cast(unsigned, tt) & 0x7fff7fffu;
                    h2 d = __builtin_bit_cast(h2, au) + one;      // v_pk_add_f16

                    // rcp of both halves on the trans pipe (no op_sel on
                    // CDNA VOP1 f16 -> compiler extracts/packs the hi half)
                    h2 rc;
                    rc.x = __builtin_amdgcn_rcph(d.x);
                    rc.y = __builtin_amdgcn_rcph(d.y);

                    // acc += n.lo*rc.lo + n.hi*rc.hi  (fp32 accumulate)
                    acc[p] = dot2_acc(n, rc, acc[p]);
                }
            }
        }
    }

    const size_t o = (((size_t)b * Ff + f) * Hh + h0) * Ww + w;
    out[o]          = acc[0];
    out[o + Ww]     = acc[1];
    out[o + 2 * Ww] = acc[2];
    out[o + 3 * Ww] = acc[3];
}

extern "C" void kernel_launch(void* const* d_in, const int* in_sizes, int n_in,
                              void* d_out, int out_size, void* d_ws, size_t ws_size,
                              hipStream_t stream) {
    const float* x   = (const float*)d_in[0];
    const float* ncf = (const float*)d_in[1];
    const float* dcf = (const float*)d_in[2];
    float* out = (float*)d_out;

    unsigned* xpadh = (unsigned*)d_ws;            // 2.23 MB
    unsigned* nch   = xpadh + XPADH_N;            // 221 KB
    unsigned* dch   = nch + NCH_N;                // 147 KB  (total 2.6 MB < ws)

    pad_h_kernel<<<(XPADH_N + 255) / 256, 256, 0, stream>>>(x, xpadh);
    coef_h_kernel<<<(NCH_N + DCH_N + 255) / 256, 256, 0, stream>>>(ncf, dcf, nch, dch);

    dim3 grid(Ff, Hh / RPB, Bb);
    kan_h_kernel<<<grid, dim3(256), 0, stream>>>(xpadh, nch, dch, out);
}

// Round 4
// 161.981 us; speedup vs baseline: 1.3321x; 1.2953x over previous
//
#include <hip/hip_runtime.h>

// KAN-CNN via MFMA: out[b,f,h,w] = sum_{dy,dx,c} R_{f,dy,dx,c}( xpad[b,c,h+dy-1,w+dx-1] )
// R(x) = P5(x)/(1+|x*Q(x)|).
//
// R8 = R7 with the bf16-powers rounding fixed. R7's absmax 12 matched the
// predicted 2^-9 relative rounding of the B-side powers (sqrt(288)*0.6) --
// layout is proven correct, numerics were the gap. K=16 has 4 unused slots:
// spend them on a powers hi/lo split. Slot budget (per lane-half g):
//   g=0 B: [phi0..phi5, plo1, plo2]   A: [chi0..chi5, chi1, chi2]
//   g=1 B: [plo3, plo4, plo5, phi1..phi5]  A: [chi3, chi4, chi5, clo1..clo5]
// Dot = sum chi*phi + chi*plo + clo*phi  (drops clo*plo ~2^-18 and clo0*1
// ~1e-4) -> effectively f32-exact. A and B are built through the SAME
// (lane-half, elem)->slot placement so the HW k-permutation cancels; C/D map
// is the m74/m101-verified row=(r&3)+8*(r>>2)+4*(lane>>5), col=lane&31.
// Also: LDS reduction inner dim padded 32->33 (was a 32-way bank conflict).

typedef int   iv4  __attribute__((ext_vector_type(4)));
typedef short s8v  __attribute__((ext_vector_type(8)));
typedef float f16v __attribute__((ext_vector_type(16)));

#define Bb 8
#define Cc 32
#define Hh 64
#define Ww 64
#define Ff 64
#define PW 66
#define PPLANE (PW * PW)             // 4356
#define NELEM  (Bb * Cc * PPLANE)    // 1,115,136 elements
#define NTAP   288
#define ACOEF_N (NTAP * 4 * 64)      // 73,728 rows of 16B = 1.18 MB

static __device__ __forceinline__ unsigned short f2bf(float f) {
    unsigned u = __builtin_bit_cast(unsigned, f);
    u += 0x7fffu + ((u >> 16) & 1u);           // RNE
    return (unsigned short)(u >> 16);
}
static __device__ __forceinline__ float bf2f(unsigned short h) {
    unsigned u = ((unsigned)h) << 16;
    return __builtin_bit_cast(float, u);
}
static __device__ __forceinline__ int pack2(unsigned short a, unsigned short b) {
    return (int)((unsigned)a | ((unsigned)b << 16));
}

// Two 16B rows per padded element, layout [g][elem] so each half-wave reads
// a contiguous 512B segment. Border elements give x=0 -> [1,0,..] rows,
// matching the zero-pad reference (R(0)=a0).
__global__ __launch_bounds__(256) void powers_kernel(
    const float* __restrict__ x, iv4* __restrict__ pw)
{
    int idx = (int)blockIdx.x * 256 + (int)threadIdx.x;   // grid exact
    int wp = idx % PW;
    int r1 = idx / PW;
    int hp = r1 % PW;
    int pl = r1 / PW;                                     // b*32+c
    float v = 0.0f;
    if (hp >= 1 && hp <= Hh && wp >= 1 && wp <= Ww)
        v = x[((size_t)pl * Hh + (hp - 1)) * Ww + (wp - 1)];
    float p1 = v, p2 = v * v, p3 = p2 * v, p4 = p2 * p2, p5 = p4 * v;
    float pv[6] = {1.0f, p1, p2, p3, p4, p5};
    unsigned short hi[6], lo[6];
#pragma unroll
    for (int e = 0; e < 6; ++e) {
        hi[e] = f2bf(pv[e]);
        lo[e] = f2bf(pv[e] - bf2f(hi[e]));
    }
    iv4 r0, r1v;
    r0.x  = pack2(hi[0], hi[1]); r0.y  = pack2(hi[2], hi[3]);
    r0.z  = pack2(hi[4], hi[5]); r0.w  = pack2(lo[1], lo[2]);
    r1v.x = pack2(lo[3], lo[4]); r1v.y = pack2(lo[5], hi[1]);
    r1v.z = pack2(hi[2], hi[3]); r1v.w = pack2(hi[4], hi[5]);
    pw[idx]         = r0;    // g=0 plane
    pw[NELEM + idx] = r1v;   // g=1 plane
}

// A fragments, load-order [t(288)][Mtile(4)][lane(64)] x 16B.
// Mtiles 0,1 = num f 0-31 / 32-63 ; tiles 2,3 = den (t = x*Q uses powers 1..4).
__global__ __launch_bounds__(256) void acoef_kernel(
    const float* __restrict__ ncf, const float* __restrict__ dcf,
    iv4* __restrict__ ac)
{
    int idx = (int)blockIdx.x * 256 + (int)threadIdx.x;   // = t*256+tile*64+l
    int l = idx & 63, tile = (idx >> 6) & 3, t = idx >> 8;
    int m = l & 31, g = l >> 5;
    float cv[6];
    if (tile < 2) {
        int f = tile * 32 + m;
        const float* s = ncf + ((size_t)f * NTAP + t) * 6;
        cv[0] = s[0]; cv[1] = s[1]; cv[2] = s[2];
        cv[3] = s[3]; cv[4] = s[4]; cv[5] = s[5];
    } else {
        int f = (tile - 2) * 32 + m;
        const float* s = dcf + ((size_t)f * NTAP + t) * 4;
        cv[0] = 0.0f; cv[1] = s[0]; cv[2] = s[1];
        cv[3] = s[2]; cv[4] = s[3]; cv[5] = 0.0f;
    }
    unsigned short chi[6], clo[6];
#pragma unroll
    for (int e = 0; e < 6; ++e) {
        chi[e] = f2bf(cv[e]);
        clo[e] = f2bf(cv[e] - bf2f(chi[e]));
    }
    iv4 o;
    if (g == 0) {   // pairs with [phi0..phi5, plo1, plo2]
        o.x = pack2(chi[0], chi[1]); o.y = pack2(chi[2], chi[3]);
        o.z = pack2(chi[4], chi[5]); o.w = pack2(chi[1], chi[2]);
    } else {        // pairs with [plo3, plo4, plo5, phi1..phi5]
        o.x = pack2(chi[3], chi[4]); o.y = pack2(chi[5], clo[1]);
        o.z = pack2(clo[2], clo[3]); o.w = pack2(clo[4], clo[5]);
    }
    ac[idx] = o;
}

// 1024 blocks x 256. Block = (b, h, w-half of 32 px); wave v handles taps
// [72v, 72v+72); LDS reduce combines the 4 partials.
__global__ __launch_bounds__(256, 4) void kan_mfma_kernel(
    const iv4* __restrict__ pw, const iv4* __restrict__ ac,
    float* __restrict__ out)
{
    const int tid = threadIdx.x;
    const int l = tid & 63, v = tid >> 6, ln = l & 31, g = l >> 5;
    const int gb = (int)blockIdx.x;
    const int wh = gb & 1, h = (gb >> 1) & 63, bb = gb >> 7;
    const int w0 = wh << 5;

    __shared__ float red[4][64][33];   // pad 33: avoid 32-way bank conflict

    f16v acc0, acc1, zf;
#pragma unroll
    for (int r = 0; r < 16; ++r) { acc0[r] = 0.0f; acc1[r] = 0.0f; zf[r] = 0.0f; }

    const iv4* __restrict__ pwg = pw + (size_t)g * NELEM;

    const int tEnd = v * 72 + 72;
    for (int t = v * 72; t < tEnd; ++t) {
        const int c = t & 31, k2 = t >> 5;            // t = k2*32 + c
        const int dy = k2 / 3, dx = k2 - dy * 3;
        const int elem = ((bb * Cc + c) * PW + (h + dy)) * PW + (w0 + ln + dx);
        iv4 bl = pwg[elem];                           // half-wave: contiguous 512B
        const iv4* ap = ac + (size_t)t * 256;
        iv4 A0 = ap[l], A1 = ap[64 + l], A2 = ap[128 + l], A3 = ap[192 + l];
        s8v bF = __builtin_bit_cast(s8v, bl);

        f16v D0 = __builtin_amdgcn_mfma_f32_32x32x16_bf16(
            __builtin_bit_cast(s8v, A0), bF, zf, 0, 0, 0);
        f16v D2 = __builtin_amdgcn_mfma_f32_32x32x16_bf16(
            __builtin_bit_cast(s8v, A2), bF, zf, 0, 0, 0);
#pragma unroll
        for (int r = 0; r < 16; ++r) {
            float dd = 1.0f + __builtin_fabsf(D2[r]);
            float rc = __builtin_amdgcn_rcpf(dd);
            acc0[r] = __builtin_fmaf(D0[r], rc, acc0[r]);
        }
        f16v D1 = __builtin_amdgcn_mfma_f32_32x32x16_bf16(
            __builtin_bit_cast(s8v, A1), bF, zf, 0, 0, 0);
        f16v D3 = __builtin_amdgcn_mfma_f32_32x32x16_bf16(
            __builtin_bit_cast(s8v, A3), bF, zf, 0, 0, 0);
#pragma unroll
        for (int r = 0; r < 16; ++r) {
            float dd = 1.0f + __builtin_fabsf(D3[r]);
            float rc = __builtin_amdgcn_rcpf(dd);
            acc1[r] = __builtin_fmaf(D1[r], rc, acc1[r]);
        }
    }

#pragma unroll
    for (int r = 0; r < 16; ++r) {
        red[v][l][r]      = acc0[r];
        red[v][l][16 + r] = acc1[r];
    }
    __syncthreads();

#pragma unroll
    for (int jj = 0; jj < 8; ++jj) {
        int j = v * 8 + jj;
        float s = red[0][l][j] + red[1][l][j] + red[2][l][j] + red[3][l][j];
        int tt = j >> 4, r = j & 15;
        // C/D map (m74/m101): col = lane&31, row = (r&3) + 8*(r>>2) + 4*(lane>>5)
        int f = tt * 32 + (r & 3) + ((r >> 2) << 3) + ((l >> 5) << 2);
        out[(((size_t)bb * Ff + f) * Hh + h) * Ww + w0 + ln] = s;
    }
}

extern "C" void kernel_launch(void* const* d_in, const int* in_sizes, int n_in,
                              void* d_out, int out_size, void* d_ws, size_t ws_size,
                              hipStream_t stream) {
    const float* x   = (const float*)d_in[0];
    const float* ncf = (const float*)d_in[1];
    const float* dcf = (const float*)d_in[2];
    float* out = (float*)d_out;

    iv4* pw = (iv4*)d_ws;            // 2 * 17.84 MB
    iv4* ac = pw + 2 * NELEM;        // 1.18 MB  (total ~36.9 MB)

    powers_kernel<<<NELEM / 256, 256, 0, stream>>>(x, pw);        // 4356 blocks
    acoef_kernel<<<NTAP, 256, 0, stream>>>(ncf, dcf, ac);         // 288 blocks
    kan_mfma_kernel<<<1024, 256, 0, stream>>>(pw, ac, out);
}